// Round 1
// baseline (2930.022 us; speedup 1.0000x reference)
//
#include <hip/hip_runtime.h>
#include <hip/hip_bf16.h>
#include <math.h>

// Problem constants (reference: N=256, D=512, H=512, EPS=1.0)
#define NB   256
#define DD   512
#define HH   512
#define CG_ITERS 16

__device__ __forceinline__ float sigmoidf_(float v) { return 1.0f / (1.0f + expf(-v)); }

// ---------------------------------------------------------------------------
// Kernel 1: z = x@Wih^T + hx@Whh^T + bih + bhh        z: [256 x 2048]
// A = concat(x,hx) along K (K=1024), B rows = Wih/Whh rows (j = output col).
// 64x64 tile, 256 threads, 4x4 micro-tile, K-tile 16.
// ---------------------------------------------------------------------------
__global__ __launch_bounds__(256) void k_gemm_z(
    const float* __restrict__ x, const float* __restrict__ hx,
    const float* __restrict__ Wih, const float* __restrict__ Whh,
    const float* __restrict__ bih, const float* __restrict__ bhh,
    float* __restrict__ z)
{
    __shared__ float As[16][65];
    __shared__ float Bs[16][65];
    const int j0 = blockIdx.x * 64;   // output gate col 0..2047
    const int n0 = blockIdx.y * 64;   // batch row
    const int t  = threadIdx.x;
    const int lr = t >> 2;            // 0..63
    const int lk = (t & 3) * 4;       // 0,4,8,12
    const int tx = t & 15, ty = t >> 4;
    float acc[4][4] = {};
    for (int k0 = 0; k0 < 1024; k0 += 16) {
        const float* Ap_ = (k0 < 512) ? x   : hx;
        const float* Bp_ = (k0 < 512) ? Wih : Whh;
        const int kk = (k0 < 512) ? k0 : (k0 - 512);
        float4 av = *(const float4*)(Ap_ + (size_t)(n0 + lr) * DD + kk + lk);
        float4 bv = *(const float4*)(Bp_ + (size_t)(j0 + lr) * DD + kk + lk);
        As[lk + 0][lr] = av.x; As[lk + 1][lr] = av.y; As[lk + 2][lr] = av.z; As[lk + 3][lr] = av.w;
        Bs[lk + 0][lr] = bv.x; Bs[lk + 1][lr] = bv.y; Bs[lk + 2][lr] = bv.z; Bs[lk + 3][lr] = bv.w;
        __syncthreads();
        #pragma unroll
        for (int k = 0; k < 16; ++k) {
            float a_[4], b_[4];
            #pragma unroll
            for (int i = 0; i < 4; ++i) { a_[i] = As[k][ty * 4 + i]; b_[i] = Bs[k][tx * 4 + i]; }
            #pragma unroll
            for (int i = 0; i < 4; ++i)
                #pragma unroll
                for (int j = 0; j < 4; ++j) acc[i][j] += a_[i] * b_[j];
        }
        __syncthreads();
    }
    #pragma unroll
    for (int i = 0; i < 4; ++i) {
        const int n = n0 + ty * 4 + i;
        #pragma unroll
        for (int j = 0; j < 4; ++j) {
            const int c = j0 + tx * 4 + j;
            z[(size_t)n * 2048 + c] = acc[i][j] + bih[c] + bhh[c];
        }
    }
}

// ---------------------------------------------------------------------------
// Kernel 2: gates + c_new + h_new + Jacobian coefficients + CG init.
// One block per batch row n. Writes h_new to out[0:N*H].
// r = p = c_new (b of the solve), xsol = 0, rho[n] = ||c_new||^2.
// ---------------------------------------------------------------------------
__global__ __launch_bounds__(256) void k_gates_init(
    const float* __restrict__ z, const float* __restrict__ cx,
    float* __restrict__ hOut, float* __restrict__ c_new,
    float* __restrict__ Ci, float* __restrict__ Cf, float* __restrict__ Cg,
    float* __restrict__ xsol, float* __restrict__ r, float* __restrict__ p,
    float* __restrict__ rho)
{
    __shared__ float red[256];
    const int n = blockIdx.x, t = threadIdx.x;
    const float* zr = z + (size_t)n * 2048;
    float part = 0.0f;
    #pragma unroll
    for (int h = t; h < HH; h += 256) {
        const float zi = zr[h], zf = zr[512 + h], zg = zr[1024 + h], zo = zr[1536 + h];
        const float iv = sigmoidf_(zi);
        const float fv = sigmoidf_(zf);
        const float gv = tanhf(zg);
        const float ov = sigmoidf_(zo);
        const float cxv = cx[(size_t)n * HH + h];
        const float cn = fv * cxv + iv * gv;
        const size_t idx = (size_t)n * HH + h;
        hOut[idx]  = ov * tanhf(cn);
        c_new[idx] = cn;
        Ci[idx] = iv * (1.0f - iv) * gv;
        Cf[idx] = fv * (1.0f - fv) * cxv;
        Cg[idx] = (1.0f - gv * gv) * iv;
        xsol[idx] = 0.0f;
        r[idx] = cn;
        p[idx] = cn;
        part += cn * cn;
    }
    red[t] = part; __syncthreads();
    for (int s = 128; s > 0; s >>= 1) { if (t < s) red[t] += red[t + s]; __syncthreads(); }
    if (t == 0) rho[n] = red[0];
}

// ---------------------------------------------------------------------------
// Kernel 3: Q = [Ci*p, Cf*p, Cg*p] @ Wih[0:1536,:]       Q: [256 x 512], K=1536
// 32x64 tile (n x d), 256 threads, 2x4 micro.
// ---------------------------------------------------------------------------
__global__ __launch_bounds__(256) void k_gemm_q(
    const float* __restrict__ Wih,
    const float* __restrict__ Ci, const float* __restrict__ Cf, const float* __restrict__ Cg,
    const float* __restrict__ p, float* __restrict__ Q)
{
    __shared__ float As[16][33];   // [k][n]
    __shared__ float Bs[16][65];   // [k][d]
    const int d0 = blockIdx.x * 64;
    const int n0 = blockIdx.y * 32;
    const int t  = threadIdx.x;
    const int ar = t >> 3, ak = (t & 7) * 2;    // A: 32 rows x 16 k, float2
    const int bk = t >> 4, bd = (t & 15) * 4;   // B: 16 k x 64 d, float4
    const int tx = t & 15, ty = t >> 4;
    float acc[2][4] = {};
    for (int k0 = 0; k0 < 1536; k0 += 16) {
        const int a = k0 >> 9;                  // uniform over tile: 0,1,2
        const float* Ca = (a == 0) ? Ci : ((a == 1) ? Cf : Cg);
        const int j = (k0 & 511) + ak;          // col within H block
        float2 cv = *(const float2*)(Ca + (size_t)(n0 + ar) * HH + j);
        float2 pv = *(const float2*)(p  + (size_t)(n0 + ar) * HH + j);
        As[ak + 0][ar] = cv.x * pv.x;
        As[ak + 1][ar] = cv.y * pv.y;
        float4 bv = *(const float4*)(Wih + (size_t)(k0 + bk) * DD + d0 + bd);
        Bs[bk][bd + 0] = bv.x; Bs[bk][bd + 1] = bv.y; Bs[bk][bd + 2] = bv.z; Bs[bk][bd + 3] = bv.w;
        __syncthreads();
        #pragma unroll
        for (int k = 0; k < 16; ++k) {
            float a_[2], b_[4];
            a_[0] = As[k][ty * 2 + 0]; a_[1] = As[k][ty * 2 + 1];
            #pragma unroll
            for (int j2 = 0; j2 < 4; ++j2) b_[j2] = Bs[k][tx * 4 + j2];
            #pragma unroll
            for (int i = 0; i < 2; ++i)
                #pragma unroll
                for (int j2 = 0; j2 < 4; ++j2) acc[i][j2] += a_[i] * b_[j2];
        }
        __syncthreads();
    }
    #pragma unroll
    for (int i = 0; i < 2; ++i)
        #pragma unroll
        for (int j2 = 0; j2 < 4; ++j2)
            Q[(size_t)(n0 + ty * 2 + i) * DD + d0 + tx * 4 + j2] = acc[i][j2];
}

// ---------------------------------------------------------------------------
// Kernel 4: Ap[n,j] = p[n,j] + Ci*(Q@Wi^T) + Cf*(Q@Wf^T) + Cg*(Q@Wg^T)
// out [256 x 512] over (n,j), K=512 (d). 3 accumulator sets.
// ---------------------------------------------------------------------------
__global__ __launch_bounds__(256) void k_gemm_ap(
    const float* __restrict__ Wih, const float* __restrict__ Q,
    const float* __restrict__ p,
    const float* __restrict__ Ci, const float* __restrict__ Cf, const float* __restrict__ Cg,
    float* __restrict__ Ap)
{
    __shared__ float As[16][33];      // [d][n]   from Q
    __shared__ float Bs[3][16][65];   // [a][d][j] from Wih rows a*512+j
    const int j0 = blockIdx.x * 64;
    const int n0 = blockIdx.y * 32;
    const int t  = threadIdx.x;
    const int ar = t >> 3, ak = (t & 7) * 2;   // A: 32 n x 16 d
    const int bj = t >> 2, bd = (t & 3) * 4;   // B: 64 j x 16 d per a
    const int tx = t & 15, ty = t >> 4;
    float acc[3][2][4] = {};
    for (int k0 = 0; k0 < 512; k0 += 16) {
        float2 qv = *(const float2*)(Q + (size_t)(n0 + ar) * DD + k0 + ak);
        As[ak + 0][ar] = qv.x;
        As[ak + 1][ar] = qv.y;
        #pragma unroll
        for (int a = 0; a < 3; ++a) {
            float4 bv = *(const float4*)(Wih + (size_t)(a * 512 + j0 + bj) * DD + k0 + bd);
            Bs[a][bd + 0][bj] = bv.x; Bs[a][bd + 1][bj] = bv.y;
            Bs[a][bd + 2][bj] = bv.z; Bs[a][bd + 3][bj] = bv.w;
        }
        __syncthreads();
        #pragma unroll
        for (int k = 0; k < 16; ++k) {
            float a_[2];
            a_[0] = As[k][ty * 2 + 0]; a_[1] = As[k][ty * 2 + 1];
            #pragma unroll
            for (int a = 0; a < 3; ++a) {
                float b_[4];
                #pragma unroll
                for (int j2 = 0; j2 < 4; ++j2) b_[j2] = Bs[a][k][tx * 4 + j2];
                #pragma unroll
                for (int i = 0; i < 2; ++i)
                    #pragma unroll
                    for (int j2 = 0; j2 < 4; ++j2) acc[a][i][j2] += a_[i] * b_[j2];
            }
        }
        __syncthreads();
    }
    #pragma unroll
    for (int i = 0; i < 2; ++i) {
        const int n = n0 + ty * 2 + i;
        #pragma unroll
        for (int j2 = 0; j2 < 4; ++j2) {
            const size_t idx = (size_t)n * HH + j0 + tx * 4 + j2;
            Ap[idx] = p[idx] + Ci[idx] * acc[0][i][j2]
                             + Cf[idx] * acc[1][i][j2]
                             + Cg[idx] * acc[2][i][j2];
        }
    }
}

// ---------------------------------------------------------------------------
// Kernel 5: fused CG vector step, one block per batch row n.
//   pAp = <p,Ap>; alpha = rho/pAp; x += a*p; r -= a*Ap;
//   rho_new = <r,r>; beta = rho_new/rho; p = r + beta*p; rho = rho_new.
//   If writeOut: store x into out[N*H + ...].
// ---------------------------------------------------------------------------
__global__ __launch_bounds__(256) void k_cg_update(
    float* __restrict__ xsol, float* __restrict__ r, float* __restrict__ p,
    const float* __restrict__ Ap, float* __restrict__ rho,
    float* __restrict__ outProx, int writeOut)
{
    __shared__ float red[256];
    __shared__ float sAlpha, sBeta;
    const int n = blockIdx.x, t = threadIdx.x;
    const size_t base = (size_t)n * HH + 2 * t;
    float2 pv = *(float2*)(p + base);
    float2 av = *(const float2*)(Ap + base);
    red[t] = pv.x * av.x + pv.y * av.y;
    __syncthreads();
    for (int s = 128; s > 0; s >>= 1) { if (t < s) red[t] += red[t + s]; __syncthreads(); }
    if (t == 0) sAlpha = rho[n] / fmaxf(red[0], 1e-30f);
    __syncthreads();
    const float alpha = sAlpha;
    float2 xv = *(float2*)(xsol + base);
    xv.x += alpha * pv.x; xv.y += alpha * pv.y;
    *(float2*)(xsol + base) = xv;
    float2 rv = *(float2*)(r + base);
    rv.x -= alpha * av.x; rv.y -= alpha * av.y;
    *(float2*)(r + base) = rv;
    red[t] = rv.x * rv.x + rv.y * rv.y;
    __syncthreads();
    for (int s = 128; s > 0; s >>= 1) { if (t < s) red[t] += red[t + s]; __syncthreads(); }
    if (t == 0) { const float rn = red[0]; sBeta = rn / fmaxf(rho[n], 1e-30f); rho[n] = rn; }
    __syncthreads();
    const float beta = sBeta;
    pv.x = rv.x + beta * pv.x; pv.y = rv.y + beta * pv.y;
    *(float2*)(p + base) = pv;
    if (writeOut) { *(float2*)(outProx + base) = xv; }
}

// ---------------------------------------------------------------------------
extern "C" void kernel_launch(void* const* d_in, const int* in_sizes, int n_in,
                              void* d_out, int out_size, void* d_ws, size_t ws_size,
                              hipStream_t stream) {
    const float* x   = (const float*)d_in[0];
    const float* hx  = (const float*)d_in[1];
    const float* cx  = (const float*)d_in[2];
    const float* Wih = (const float*)d_in[3];
    const float* Whh = (const float*)d_in[4];
    const float* bih = (const float*)d_in[5];
    const float* bhh = (const float*)d_in[6];
    float* out = (float*)d_out;              // [h_new (131072) | prox_c (131072)]

    float* ws = (float*)d_ws;
    const size_t NH = (size_t)NB * HH;       // 131072
    float* z     = ws;                        // 256*2048 = 524288
    float* c_new = z + 524288;
    float* Ci    = c_new + NH;
    float* Cf    = Ci + NH;
    float* Cg    = Cf + NH;
    float* xsol  = Cg + NH;
    float* r     = xsol + NH;
    float* p     = r + NH;
    float* Q     = p + NH;
    float* Ap    = Q + NH;
    float* rho   = Ap + NH;                   // 256 floats

    k_gemm_z<<<dim3(32, 4), 256, 0, stream>>>(x, hx, Wih, Whh, bih, bhh, z);
    k_gates_init<<<NB, 256, 0, stream>>>(z, cx, out, c_new, Ci, Cf, Cg, xsol, r, p, rho);

    for (int it = 0; it < CG_ITERS; ++it) {
        k_gemm_q<<<dim3(8, 8), 256, 0, stream>>>(Wih, Ci, Cf, Cg, p, Q);
        k_gemm_ap<<<dim3(8, 8), 256, 0, stream>>>(Wih, Q, p, Ci, Cf, Cg, Ap);
        k_cg_update<<<NB, 256, 0, stream>>>(xsol, r, p, Ap, rho, out + NH,
                                            (it == CG_ITERS - 1) ? 1 : 0);
    }
}

// Round 2
// 772.399 us; speedup vs baseline: 3.7934x; 3.7934x over previous
//
#include <hip/hip_runtime.h>
#include <math.h>

// Problem constants (reference: N=256, D=512, H=512, EPS=1.0)
#define NB   256
#define DD   512
#define HH   512
#define NH   (NB * HH)        // 131072
#define CG_ITERS 16
#define KSLAB 8

__device__ __forceinline__ float sigmoidf_(float v) { return 1.0f / (1.0f + expf(-v)); }

// ---------------------------------------------------------------------------
// Kernel 1: z = x@Wih^T + hx@Whh^T + bih + bhh        z: [256 x 2048]
// Tile 32n x 64j, K=1024. Grid (32 j-tiles, 8 n-tiles) = 256 blocks.
// ---------------------------------------------------------------------------
__global__ __launch_bounds__(256) void k_gemm_z(
    const float* __restrict__ x, const float* __restrict__ hx,
    const float* __restrict__ Wih, const float* __restrict__ Whh,
    const float* __restrict__ bih, const float* __restrict__ bhh,
    float* __restrict__ z)
{
    __shared__ float As[16][34];   // [k][n]  (pad 34: transposed stores 2-way max)
    __shared__ float Bs[16][66];   // [k][j]  (pad 66: transposed stores 2-way max)
    const int j0 = blockIdx.x * 64;
    const int n0 = blockIdx.y * 32;
    const int t  = threadIdx.x;
    const int an = t >> 3, ak2 = (t & 7) * 2;   // A: 32 rows x 16 k (float2)
    const int br = t >> 2, bk4 = (t & 3) * 4;   // B: 64 rows x 16 k (float4)
    const int tx = t & 15, ty = t >> 4;
    float acc[2][4] = {};
    for (int k0 = 0; k0 < 1024; k0 += 16) {
        const float* Apt = (k0 < 512) ? x   : hx;
        const float* Bpt = (k0 < 512) ? Wih : Whh;
        const int kk = k0 & 511;
        float2 av = *(const float2*)(Apt + (size_t)(n0 + an) * DD + kk + ak2);
        As[ak2 + 0][an] = av.x; As[ak2 + 1][an] = av.y;
        float4 bv = *(const float4*)(Bpt + (size_t)(j0 + br) * DD + kk + bk4);
        Bs[bk4 + 0][br] = bv.x; Bs[bk4 + 1][br] = bv.y;
        Bs[bk4 + 2][br] = bv.z; Bs[bk4 + 3][br] = bv.w;
        __syncthreads();
        #pragma unroll
        for (int k = 0; k < 16; ++k) {
            float a_[2], b_[4];
            a_[0] = As[k][ty * 2 + 0]; a_[1] = As[k][ty * 2 + 1];
            #pragma unroll
            for (int jj = 0; jj < 4; ++jj) b_[jj] = Bs[k][tx * 4 + jj];
            #pragma unroll
            for (int i = 0; i < 2; ++i)
                #pragma unroll
                for (int jj = 0; jj < 4; ++jj) acc[i][jj] += a_[i] * b_[jj];
        }
        __syncthreads();
    }
    #pragma unroll
    for (int i = 0; i < 2; ++i) {
        const int n = n0 + ty * 2 + i;
        #pragma unroll
        for (int jj = 0; jj < 4; ++jj) {
            const int c = j0 + tx * 4 + jj;
            z[(size_t)n * 2048 + c] = acc[i][jj] + bih[c] + bhh[c];
        }
    }
}

// ---------------------------------------------------------------------------
// Kernel 2: gates + c_new + h_new + Jacobian coefficients + CG init.
// One block per batch row n. Writes h_new to out[0:N*H].
// ---------------------------------------------------------------------------
__global__ __launch_bounds__(256) void k_gates_init(
    const float* __restrict__ z, const float* __restrict__ cx,
    float* __restrict__ hOut,
    float* __restrict__ Ci, float* __restrict__ Cf, float* __restrict__ Cg,
    float* __restrict__ xsol, float* __restrict__ r, float* __restrict__ p,
    float* __restrict__ rho)
{
    __shared__ float red[256];
    const int n = blockIdx.x, t = threadIdx.x;
    const float* zr = z + (size_t)n * 2048;
    float part = 0.0f;
    #pragma unroll
    for (int h = t; h < HH; h += 256) {
        const float zi = zr[h], zf = zr[512 + h], zg = zr[1024 + h], zo = zr[1536 + h];
        const float iv = sigmoidf_(zi);
        const float fv = sigmoidf_(zf);
        const float gv = tanhf(zg);
        const float ov = sigmoidf_(zo);
        const float cxv = cx[(size_t)n * HH + h];
        const float cn = fv * cxv + iv * gv;
        const size_t idx = (size_t)n * HH + h;
        hOut[idx]  = ov * tanhf(cn);
        Ci[idx] = iv * (1.0f - iv) * gv;
        Cf[idx] = fv * (1.0f - fv) * cxv;
        Cg[idx] = (1.0f - gv * gv) * iv;
        xsol[idx] = 0.0f;
        r[idx] = cn;
        p[idx] = cn;
        part += cn * cn;
    }
    red[t] = part; __syncthreads();
    for (int s = 128; s > 0; s >>= 1) { if (t < s) red[t] += red[t + s]; __syncthreads(); }
    if (t == 0) rho[n] = red[0];
}

// ---------------------------------------------------------------------------
// Kernel 3: Qp[slab][n][d] = partial of  [Ci*p,Cf*p,Cg*p] @ Wih[0:1536,:]
// K=1536 split into 8 slabs of 192. Tile 64n x 64d.
// Grid (8 d-tiles, 4 n-tiles, 8 slabs) = 256 blocks. No atomics, no init.
// ---------------------------------------------------------------------------
__global__ __launch_bounds__(256) void k_gemm_q(
    const float* __restrict__ Wih,
    const float* __restrict__ Ci, const float* __restrict__ Cf, const float* __restrict__ Cg,
    const float* __restrict__ p, float* __restrict__ Qp)
{
    __shared__ float As[16][66];   // [k][n] transposed stores (pad 66 -> 2-way max)
    __shared__ float Bs[16][65];   // [k][d] row-major stores (pad 65 -> 2-way max)
    const int d0 = blockIdx.x * 64;
    const int n0 = blockIdx.y * 64;
    const int sl = blockIdx.z;
    const int t  = threadIdx.x;
    const int an = t >> 2, ak4 = (t & 3) * 4;    // A: 64 n x 16 k (float4)
    const int wk = t >> 4, wd4 = (t & 15) * 4;   // W: 16 k x 64 d (float4)
    const int tx = t & 15, ty = t >> 4;
    float acc[4][4] = {};
    for (int kc = 0; kc < 192; kc += 16) {
        const int kg = sl * 192 + kc;            // global k, multiple of 16
        const int ga = kg >> 9;                  // gate region uniform per 16-run
        const float* Ca = (ga == 0) ? Ci : ((ga == 1) ? Cf : Cg);
        const int j = (kg & 511) + ak4;
        float4 cv = *(const float4*)(Ca + (size_t)(n0 + an) * HH + j);
        float4 pv = *(const float4*)(p  + (size_t)(n0 + an) * HH + j);
        As[ak4 + 0][an] = cv.x * pv.x; As[ak4 + 1][an] = cv.y * pv.y;
        As[ak4 + 2][an] = cv.z * pv.z; As[ak4 + 3][an] = cv.w * pv.w;
        float4 wv = *(const float4*)(Wih + (size_t)(kg + wk) * DD + d0 + wd4);
        Bs[wk][wd4 + 0] = wv.x; Bs[wk][wd4 + 1] = wv.y;
        Bs[wk][wd4 + 2] = wv.z; Bs[wk][wd4 + 3] = wv.w;
        __syncthreads();
        #pragma unroll
        for (int k = 0; k < 16; ++k) {
            float a_[4], b_[4];
            #pragma unroll
            for (int i = 0; i < 4; ++i) a_[i] = As[k][ty * 4 + i];
            #pragma unroll
            for (int jj = 0; jj < 4; ++jj) b_[jj] = Bs[k][tx * 4 + jj];
            #pragma unroll
            for (int i = 0; i < 4; ++i)
                #pragma unroll
                for (int jj = 0; jj < 4; ++jj) acc[i][jj] += a_[i] * b_[jj];
        }
        __syncthreads();
    }
    float* Qs = Qp + (size_t)sl * NH;
    #pragma unroll
    for (int i = 0; i < 4; ++i)
        #pragma unroll
        for (int jj = 0; jj < 4; ++jj)
            Qs[(size_t)(n0 + ty * 4 + i) * DD + d0 + tx * 4 + jj] = acc[i][jj];
}

// ---------------------------------------------------------------------------
// Kernel 4: Vp[slab][n][j] = partial of Sum_a Ca .* (U @ Wa^T), U = sum_s Qp[s]
// K=512 (d) split into 8 slabs of 64. Tile 64n x 64j, 3 accumulator sets.
// Slab-sum of Qp is folded into A staging. Grid (8 j, 4 n, 8 slabs) = 256.
// ---------------------------------------------------------------------------
__global__ __launch_bounds__(256) void k_gemm_ap(
    const float* __restrict__ Wih, const float* __restrict__ Qp,
    const float* __restrict__ Ci, const float* __restrict__ Cf, const float* __restrict__ Cg,
    float* __restrict__ Vp)
{
    __shared__ float As[16][66];      // [d][n]
    __shared__ float Bs[3][16][66];   // [a][d][j]
    const int j0 = blockIdx.x * 64;
    const int n0 = blockIdx.y * 64;
    const int sl = blockIdx.z;                   // d-chunk
    const int t  = threadIdx.x;
    const int an = t >> 2, ad4 = (t & 3) * 4;    // A: 64 n x 16 d
    const int wj = t >> 2, wdb = (t & 3) * 4;    // B: 64 j x 16 d per gate
    const int tx = t & 15, ty = t >> 4;
    float acc[3][4][4] = {};
    for (int kc = 0; kc < 64; kc += 16) {
        const int dg = sl * 64 + kc;
        float4 us = make_float4(0.f, 0.f, 0.f, 0.f);
        #pragma unroll
        for (int q = 0; q < KSLAB; ++q) {
            float4 v = *(const float4*)(Qp + (size_t)q * NH + (size_t)(n0 + an) * DD + dg + ad4);
            us.x += v.x; us.y += v.y; us.z += v.z; us.w += v.w;
        }
        As[ad4 + 0][an] = us.x; As[ad4 + 1][an] = us.y;
        As[ad4 + 2][an] = us.z; As[ad4 + 3][an] = us.w;
        #pragma unroll
        for (int a = 0; a < 3; ++a) {
            float4 wv = *(const float4*)(Wih + (size_t)(a * 512 + j0 + wj) * DD + dg + wdb);
            Bs[a][wdb + 0][wj] = wv.x; Bs[a][wdb + 1][wj] = wv.y;
            Bs[a][wdb + 2][wj] = wv.z; Bs[a][wdb + 3][wj] = wv.w;
        }
        __syncthreads();
        #pragma unroll
        for (int k = 0; k < 16; ++k) {
            float a_[4], b_[3][4];
            #pragma unroll
            for (int i = 0; i < 4; ++i) a_[i] = As[k][ty * 4 + i];
            #pragma unroll
            for (int a = 0; a < 3; ++a)
                #pragma unroll
                for (int jj = 0; jj < 4; ++jj) b_[a][jj] = Bs[a][k][tx * 4 + jj];
            #pragma unroll
            for (int a = 0; a < 3; ++a)
                #pragma unroll
                for (int i = 0; i < 4; ++i)
                    #pragma unroll
                    for (int jj = 0; jj < 4; ++jj) acc[a][i][jj] += a_[i] * b_[a][jj];
        }
        __syncthreads();
    }
    float* Vs = Vp + (size_t)sl * NH;
    #pragma unroll
    for (int i = 0; i < 4; ++i) {
        const int n = n0 + ty * 4 + i;
        #pragma unroll
        for (int jj = 0; jj < 4; ++jj) {
            const size_t idx = (size_t)n * HH + j0 + tx * 4 + jj;
            Vs[idx] = Ci[idx] * acc[0][i][jj]
                    + Cf[idx] * acc[1][i][jj]
                    + Cg[idx] * acc[2][i][jj];
        }
    }
}

// ---------------------------------------------------------------------------
// Kernel 5: fused CG vector step; Ap formed on the fly as p + sum_s Vp[s].
// One block per batch row n.
// ---------------------------------------------------------------------------
__global__ __launch_bounds__(256) void k_cg_update(
    float* __restrict__ xsol, float* __restrict__ r, float* __restrict__ p,
    const float* __restrict__ Vp, float* __restrict__ rho,
    float* __restrict__ outProx, int writeOut)
{
    __shared__ float red[256];
    __shared__ float sAlpha, sBeta;
    const int n = blockIdx.x, t = threadIdx.x;
    const size_t base = (size_t)n * HH + 2 * t;
    float2 pv = *(float2*)(p + base);
    float2 av = pv;                       // Ap = p + sum_s Vp[s]
    #pragma unroll
    for (int s = 0; s < KSLAB; ++s) {
        float2 v = *(const float2*)(Vp + (size_t)s * NH + base);
        av.x += v.x; av.y += v.y;
    }
    red[t] = pv.x * av.x + pv.y * av.y;
    __syncthreads();
    for (int s = 128; s > 0; s >>= 1) { if (t < s) red[t] += red[t + s]; __syncthreads(); }
    if (t == 0) sAlpha = rho[n] / fmaxf(red[0], 1e-30f);
    __syncthreads();
    const float alpha = sAlpha;
    float2 xv = *(float2*)(xsol + base);
    xv.x += alpha * pv.x; xv.y += alpha * pv.y;
    *(float2*)(xsol + base) = xv;
    float2 rv = *(float2*)(r + base);
    rv.x -= alpha * av.x; rv.y -= alpha * av.y;
    *(float2*)(r + base) = rv;
    red[t] = rv.x * rv.x + rv.y * rv.y;
    __syncthreads();
    for (int s = 128; s > 0; s >>= 1) { if (t < s) red[t] += red[t + s]; __syncthreads(); }
    if (t == 0) { const float rn = red[0]; sBeta = rn / fmaxf(rho[n], 1e-30f); rho[n] = rn; }
    __syncthreads();
    const float beta = sBeta;
    pv.x = rv.x + beta * pv.x; pv.y = rv.y + beta * pv.y;
    *(float2*)(p + base) = pv;
    if (writeOut) { *(float2*)(outProx + base) = xv; }
}

// ---------------------------------------------------------------------------
extern "C" void kernel_launch(void* const* d_in, const int* in_sizes, int n_in,
                              void* d_out, int out_size, void* d_ws, size_t ws_size,
                              hipStream_t stream) {
    const float* x   = (const float*)d_in[0];
    const float* hx  = (const float*)d_in[1];
    const float* cx  = (const float*)d_in[2];
    const float* Wih = (const float*)d_in[3];
    const float* Whh = (const float*)d_in[4];
    const float* bih = (const float*)d_in[5];
    const float* bhh = (const float*)d_in[6];
    float* out = (float*)d_out;              // [h_new (131072) | prox_c (131072)]

    float* ws = (float*)d_ws;
    float* z    = ws;                        // 256*2048 = 524288
    float* Ci   = z + 524288;
    float* Cf   = Ci + NH;
    float* Cg   = Cf + NH;
    float* xsol = Cg + NH;
    float* r    = xsol + NH;
    float* p    = r + NH;
    float* Qp   = p + NH;                    // 8 * NH
    float* Vp   = Qp + (size_t)KSLAB * NH;   // 8 * NH
    float* rho  = Vp + (size_t)KSLAB * NH;   // 256 floats

    k_gemm_z<<<dim3(32, 8), 256, 0, stream>>>(x, hx, Wih, Whh, bih, bhh, z);
    k_gates_init<<<NB, 256, 0, stream>>>(z, cx, out, Ci, Cf, Cg, xsol, r, p, rho);

    for (int it = 0; it < CG_ITERS; ++it) {
        k_gemm_q<<<dim3(8, 4, KSLAB), 256, 0, stream>>>(Wih, Ci, Cf, Cg, p, Qp);
        k_gemm_ap<<<dim3(8, 4, KSLAB), 256, 0, stream>>>(Wih, Qp, Ci, Cf, Cg, Vp);
        k_cg_update<<<NB, 256, 0, stream>>>(xsol, r, p, Vp, rho, out + NH,
                                            (it == CG_ITERS - 1) ? 1 : 0);
    }
}

// Round 3
// 445.743 us; speedup vs baseline: 6.5733x; 1.7328x over previous
//
#include <hip/hip_runtime.h>
#include <math.h>

// Problem constants (reference: N=256, D=512, H=512, EPS=1.0)
#define NB   256
#define DD   512
#define HH   512
#define NH   (NB * HH)        // 131072
#define CG_ITERS 16
#define KSLAB 8

typedef __attribute__((ext_vector_type(8))) short   short8v;   // 8 x bf16 (4 VGPR)
typedef __attribute__((ext_vector_type(4))) float   f32x4;     // MFMA acc
typedef __attribute__((ext_vector_type(4))) unsigned short ushort4v;

__device__ __forceinline__ float sigmoidf_(float v) { return 1.0f / (1.0f + expf(-v)); }

// fp32 -> bf16 round-to-nearest-even
__device__ __forceinline__ unsigned short f2bf(float f) {
    union { float f; unsigned int u; } v; v.f = f;
    return (unsigned short)((v.u + 0x7FFFu + ((v.u >> 16) & 1u)) >> 16);
}

// Swizzled LDS index (in shorts) for 64-col (128B) bf16 rows, 16B slots.
// slot' = slot ^ (row&7)  => ds_read_b128 column reads are <=2-way (free).
__device__ __forceinline__ int swz(int row, int col8) {
    return row * 64 + ((col8 ^ (row & 7)) << 3);
}

// ---------------------------------------------------------------------------
// Prep A: elementwise fp32 -> bf16 for Wih(2048x512), Whh(2048x512), x, hx.
// ---------------------------------------------------------------------------
__global__ __launch_bounds__(256) void k_cvt(
    const float* __restrict__ Wih, const float* __restrict__ Whh,
    const float* __restrict__ x, const float* __restrict__ hx,
    unsigned short* __restrict__ Wihb, unsigned short* __restrict__ Whhb,
    unsigned short* __restrict__ xb, unsigned short* __restrict__ hxb)
{
    const int idx = (blockIdx.x * 256 + threadIdx.x) * 4;   // 2,359,296 total elems
    const float* src; unsigned short* dst; int off;
    if      (idx < 1048576) { src = Wih; dst = Wihb; off = idx; }
    else if (idx < 2097152) { src = Whh; dst = Whhb; off = idx - 1048576; }
    else if (idx < 2228224) { src = x;   dst = xb;   off = idx - 2097152; }
    else                    { src = hx;  dst = hxb;  off = idx - 2228224; }
    float4 v = *(const float4*)(src + off);
    ushort4v o;
    o[0] = f2bf(v.x); o[1] = f2bf(v.y); o[2] = f2bf(v.z); o[3] = f2bf(v.w);
    *(ushort4v*)(dst + off) = o;
}

// ---------------------------------------------------------------------------
// Prep B: Wtb[d][k] = bf16(Wih[k][d]) for k<1536  (row-major [512][1536]).
// 64x64 tiles via padded LDS. Grid (24 k-tiles, 8 d-tiles).
// ---------------------------------------------------------------------------
__global__ __launch_bounds__(256) void k_tr(
    const float* __restrict__ Wih, unsigned short* __restrict__ Wtb)
{
    __shared__ float T[64][65];
    const int k0 = blockIdx.x * 64;
    const int d0 = blockIdx.y * 64;
    const int t  = threadIdx.x;
    const int r = t >> 4, c4 = (t & 15) * 4;
    #pragma unroll
    for (int pp = 0; pp < 4; ++pp) {
        float4 v = *(const float4*)(Wih + (size_t)(k0 + pp * 16 + r) * DD + d0 + c4);
        T[pp * 16 + r][c4 + 0] = v.x; T[pp * 16 + r][c4 + 1] = v.y;
        T[pp * 16 + r][c4 + 2] = v.z; T[pp * 16 + r][c4 + 3] = v.w;
    }
    __syncthreads();
    const int dr = t >> 3, c8 = (t & 7) * 8;
    #pragma unroll
    for (int pp = 0; pp < 2; ++pp) {
        const int d = pp * 32 + dr;
        short8v o;
        #pragma unroll
        for (int e = 0; e < 8; ++e) o[e] = (short)f2bf(T[c8 + e][d]);
        *(short8v*)(Wtb + (size_t)(d0 + d) * 1536 + k0 + c8) = o;
    }
}

// ---------------------------------------------------------------------------
// Kernel 1 (MFMA): zp[sl][n][c] = partial of [x|hx] @ [Wih|Whh]^T
// Tile 64n x 64c, K=1024 split 2 (8 stages of 64). Grid (32,4,2)=256 blocks.
// ---------------------------------------------------------------------------
__global__ __launch_bounds__(256) void k_gemm_z(
    const unsigned short* __restrict__ xb, const unsigned short* __restrict__ hxb,
    const unsigned short* __restrict__ Wihb, const unsigned short* __restrict__ Whhb,
    float* __restrict__ zp)
{
    __shared__ unsigned short As[64 * 64];
    __shared__ unsigned short Bs[64 * 64];
    const int j0 = blockIdx.x * 64;
    const int n0 = blockIdx.y * 64;
    const int sl = blockIdx.z;
    const int t = threadIdx.x;
    const int w = t >> 6, lane = t & 63;
    const int wm = (w >> 1) * 32, wjn = (w & 1) * 32;
    const int fr = lane & 15, g = lane >> 4;
    const int srow = t >> 3, scol8 = t & 7;
    f32x4 acc[2][2] = {};
    for (int st = 0; st < 8; ++st) {
        const int sb = sl * 512 + st * 64;
        const unsigned short* Asrc; const unsigned short* Bsrc; int kk;
        if (sb < 512) { Asrc = xb;  Bsrc = Wihb; kk = sb; }
        else          { Asrc = hxb; Bsrc = Whhb; kk = sb - 512; }
        #pragma unroll
        for (int pp = 0; pp < 2; ++pp) {
            const int row = pp * 32 + srow;
            *(short8v*)&As[swz(row, scol8)] =
                *(const short8v*)(Asrc + (size_t)(n0 + row) * DD + kk + scol8 * 8);
            *(short8v*)&Bs[swz(row, scol8)] =
                *(const short8v*)(Bsrc + (size_t)(j0 + row) * DD + kk + scol8 * 8);
        }
        __syncthreads();
        #pragma unroll
        for (int ks = 0; ks < 2; ++ks) {
            short8v a[2], b[2];
            #pragma unroll
            for (int i = 0; i < 2; ++i) {
                a[i] = *(const short8v*)&As[swz(wm  + i * 16 + fr, ks * 4 + g)];
                b[i] = *(const short8v*)&Bs[swz(wjn + i * 16 + fr, ks * 4 + g)];
            }
            #pragma unroll
            for (int i = 0; i < 2; ++i)
                #pragma unroll
                for (int jj = 0; jj < 2; ++jj)
                    acc[i][jj] = __builtin_amdgcn_mfma_f32_16x16x32_bf16(a[i], b[jj], acc[i][jj], 0, 0, 0);
        }
        __syncthreads();
    }
    float* Z = zp + (size_t)sl * NB * 2048;
    #pragma unroll
    for (int i = 0; i < 2; ++i)
        #pragma unroll
        for (int jj = 0; jj < 2; ++jj)
            #pragma unroll
            for (int rg = 0; rg < 4; ++rg) {
                const int n = n0 + wm + i * 16 + g * 4 + rg;
                const int c = j0 + wjn + jj * 16 + fr;
                Z[(size_t)n * 2048 + c] = acc[i][jj][rg];
            }
}

// ---------------------------------------------------------------------------
// Kernel 2: gates (z = zp0+zp1+biases) + coefs + CG init. One block per n.
// ---------------------------------------------------------------------------
__global__ __launch_bounds__(256) void k_gates_init(
    const float* __restrict__ zp, const float* __restrict__ cx,
    const float* __restrict__ bih, const float* __restrict__ bhh,
    float* __restrict__ hOut,
    float* __restrict__ Ci, float* __restrict__ Cf, float* __restrict__ Cg,
    float* __restrict__ xsol, float* __restrict__ r, float* __restrict__ p,
    float* __restrict__ rho)
{
    __shared__ float red[256];
    const int n = blockIdx.x, t = threadIdx.x;
    const float* z0 = zp + (size_t)n * 2048;
    const float* z1 = zp + (size_t)NB * 2048 + (size_t)n * 2048;
    float part = 0.0f;
    #pragma unroll
    for (int h = t; h < HH; h += 256) {
        const float zi = z0[h]        + z1[h]        + bih[h]        + bhh[h];
        const float zf = z0[512 + h]  + z1[512 + h]  + bih[512 + h]  + bhh[512 + h];
        const float zg = z0[1024 + h] + z1[1024 + h] + bih[1024 + h] + bhh[1024 + h];
        const float zo = z0[1536 + h] + z1[1536 + h] + bih[1536 + h] + bhh[1536 + h];
        const float iv = sigmoidf_(zi);
        const float fv = sigmoidf_(zf);
        const float gv = tanhf(zg);
        const float ov = sigmoidf_(zo);
        const float cxv = cx[(size_t)n * HH + h];
        const float cn = fv * cxv + iv * gv;
        const size_t idx = (size_t)n * HH + h;
        hOut[idx] = ov * tanhf(cn);
        Ci[idx] = iv * (1.0f - iv) * gv;
        Cf[idx] = fv * (1.0f - fv) * cxv;
        Cg[idx] = (1.0f - gv * gv) * iv;
        xsol[idx] = 0.0f;
        r[idx] = cn;
        p[idx] = cn;
        part += cn * cn;
    }
    red[t] = part; __syncthreads();
    for (int s = 128; s > 0; s >>= 1) { if (t < s) red[t] += red[t + s]; __syncthreads(); }
    if (t == 0) rho[n] = red[0];
}

// ---------------------------------------------------------------------------
// Kernel 3 (MFMA): Qp[sl][n][d] = partial of (Ca.*p) @ Wt^T  (K=1536, 8 slabs)
// A built on the fly (fp32 mul -> bf16). Grid (8 d, 4 n, 8 sl) = 256 blocks.
// ---------------------------------------------------------------------------
__global__ __launch_bounds__(256) void k_gemm_q(
    const unsigned short* __restrict__ Wtb,
    const float* __restrict__ Ci, const float* __restrict__ Cf, const float* __restrict__ Cg,
    const float* __restrict__ p, float* __restrict__ Qp)
{
    __shared__ unsigned short As[64 * 64];
    __shared__ unsigned short Bs[64 * 64];
    const int d0 = blockIdx.x * 64;
    const int n0 = blockIdx.y * 64;
    const int sl = blockIdx.z;
    const int t = threadIdx.x;
    const int w = t >> 6, lane = t & 63;
    const int wm = (w >> 1) * 32, wd = (w & 1) * 32;
    const int fr = lane & 15, g = lane >> 4;
    const int srow = t >> 3, scol8 = t & 7;
    f32x4 acc[2][2] = {};
    for (int st = 0; st < 3; ++st) {
        const int sb = sl * 192 + st * 64;        // global k, stage within one gate
        const int ga = sb >> 9;
        const float* Ca = (ga == 0) ? Ci : ((ga == 1) ? Cf : Cg);
        const int jb = sb & 511;
        #pragma unroll
        for (int pp = 0; pp < 2; ++pp) {
            const int row = pp * 32 + srow;
            const size_t gidx = (size_t)(n0 + row) * HH + jb + scol8 * 8;
            float4 c0 = *(const float4*)(Ca + gidx), c1 = *(const float4*)(Ca + gidx + 4);
            float4 p0 = *(const float4*)(p + gidx),  p1 = *(const float4*)(p + gidx + 4);
            short8v av;
            av[0] = (short)f2bf(c0.x * p0.x); av[1] = (short)f2bf(c0.y * p0.y);
            av[2] = (short)f2bf(c0.z * p0.z); av[3] = (short)f2bf(c0.w * p0.w);
            av[4] = (short)f2bf(c1.x * p1.x); av[5] = (short)f2bf(c1.y * p1.y);
            av[6] = (short)f2bf(c1.z * p1.z); av[7] = (short)f2bf(c1.w * p1.w);
            *(short8v*)&As[swz(row, scol8)] = av;
            *(short8v*)&Bs[swz(row, scol8)] =
                *(const short8v*)(Wtb + (size_t)(d0 + row) * 1536 + sb + scol8 * 8);
        }
        __syncthreads();
        #pragma unroll
        for (int ks = 0; ks < 2; ++ks) {
            short8v a[2], b[2];
            #pragma unroll
            for (int i = 0; i < 2; ++i) {
                a[i] = *(const short8v*)&As[swz(wm + i * 16 + fr, ks * 4 + g)];
                b[i] = *(const short8v*)&Bs[swz(wd + i * 16 + fr, ks * 4 + g)];
            }
            #pragma unroll
            for (int i = 0; i < 2; ++i)
                #pragma unroll
                for (int jj = 0; jj < 2; ++jj)
                    acc[i][jj] = __builtin_amdgcn_mfma_f32_16x16x32_bf16(a[i], b[jj], acc[i][jj], 0, 0, 0);
        }
        __syncthreads();
    }
    float* Qs = Qp + (size_t)sl * NH;
    #pragma unroll
    for (int i = 0; i < 2; ++i)
        #pragma unroll
        for (int jj = 0; jj < 2; ++jj)
            #pragma unroll
            for (int rg = 0; rg < 4; ++rg) {
                const int n = n0 + wm + i * 16 + g * 4 + rg;
                const int d = d0 + wd + jj * 16 + fr;
                Qs[(size_t)n * DD + d] = acc[i][jj][rg];
            }
}

// ---------------------------------------------------------------------------
// Kernel 4 (MFMA): Vp[sl][n][j] = partial_d of Sum_a Ca .* (U @ Wa^T),
// U = sum_s Qp[s] (folded into A staging). d split 8x64. Grid (8,4,8)=256.
// ---------------------------------------------------------------------------
__global__ __launch_bounds__(256) void k_gemm_ap(
    const unsigned short* __restrict__ Wihb, const float* __restrict__ Qp,
    const float* __restrict__ Ci, const float* __restrict__ Cf, const float* __restrict__ Cg,
    float* __restrict__ Vp)
{
    __shared__ unsigned short As[64 * 64];
    __shared__ unsigned short Bs[3][64 * 64];
    const int j0 = blockIdx.x * 64;
    const int n0 = blockIdx.y * 64;
    const int sl = blockIdx.z;
    const int d0 = sl * 64;
    const int t = threadIdx.x;
    const int w = t >> 6, lane = t & 63;
    const int wm = (w >> 1) * 32, wj = (w & 1) * 32;
    const int fr = lane & 15, g = lane >> 4;
    {
        const int row = t >> 2, c16 = (t & 3) * 16;
        float u[16];
        #pragma unroll
        for (int e = 0; e < 16; ++e) u[e] = 0.0f;
        #pragma unroll
        for (int s = 0; s < KSLAB; ++s) {
            const float* Q = Qp + (size_t)s * NH + (size_t)(n0 + row) * DD + d0 + c16;
            #pragma unroll
            for (int e4 = 0; e4 < 4; ++e4) {
                float4 v = *(const float4*)(Q + e4 * 4);
                u[e4 * 4 + 0] += v.x; u[e4 * 4 + 1] += v.y;
                u[e4 * 4 + 2] += v.z; u[e4 * 4 + 3] += v.w;
            }
        }
        short8v lo, hi;
        #pragma unroll
        for (int e = 0; e < 8; ++e) { lo[e] = (short)f2bf(u[e]); hi[e] = (short)f2bf(u[8 + e]); }
        *(short8v*)&As[swz(row, (t & 3) * 2)]     = lo;
        *(short8v*)&As[swz(row, (t & 3) * 2 + 1)] = hi;
        #pragma unroll
        for (int a = 0; a < 3; ++a) {
            const unsigned short* Wr = Wihb + (size_t)(a * 512 + j0 + row) * DD + d0 + c16;
            *(short8v*)&Bs[a][swz(row, (t & 3) * 2)]     = *(const short8v*)Wr;
            *(short8v*)&Bs[a][swz(row, (t & 3) * 2 + 1)] = *(const short8v*)(Wr + 8);
        }
    }
    __syncthreads();
    f32x4 acc[3][2][2] = {};
    #pragma unroll
    for (int ks = 0; ks < 2; ++ks) {
        short8v a[2], b[3][2];
        #pragma unroll
        for (int i = 0; i < 2; ++i)
            a[i] = *(const short8v*)&As[swz(wm + i * 16 + fr, ks * 4 + g)];
        #pragma unroll
        for (int aa = 0; aa < 3; ++aa)
            #pragma unroll
            for (int i = 0; i < 2; ++i)
                b[aa][i] = *(const short8v*)&Bs[aa][swz(wj + i * 16 + fr, ks * 4 + g)];
        #pragma unroll
        for (int aa = 0; aa < 3; ++aa)
            #pragma unroll
            for (int i = 0; i < 2; ++i)
                #pragma unroll
                for (int jj = 0; jj < 2; ++jj)
                    acc[aa][i][jj] = __builtin_amdgcn_mfma_f32_16x16x32_bf16(a[i], b[aa][jj], acc[aa][i][jj], 0, 0, 0);
    }
    float* Vs = Vp + (size_t)sl * NH;
    #pragma unroll
    for (int i = 0; i < 2; ++i)
        #pragma unroll
        for (int jj = 0; jj < 2; ++jj)
            #pragma unroll
            for (int rg = 0; rg < 4; ++rg) {
                const int n = n0 + wm + i * 16 + g * 4 + rg;
                const int j = j0 + wj + jj * 16 + fr;
                const size_t idx = (size_t)n * HH + j;
                Vs[idx] = Ci[idx] * acc[0][i][jj][rg]
                        + Cf[idx] * acc[1][i][jj][rg]
                        + Cg[idx] * acc[2][i][jj][rg];
            }
}

// ---------------------------------------------------------------------------
// Kernel 5: fused CG vector step; Ap = p + sum_s Vp[s]. One block per row n.
// ---------------------------------------------------------------------------
__global__ __launch_bounds__(256) void k_cg_update(
    float* __restrict__ xsol, float* __restrict__ r, float* __restrict__ p,
    const float* __restrict__ Vp, float* __restrict__ rho,
    float* __restrict__ outProx, int writeOut)
{
    __shared__ float red[256];
    __shared__ float sAlpha, sBeta;
    const int n = blockIdx.x, t = threadIdx.x;
    const size_t base = (size_t)n * HH + 2 * t;
    float2 pv = *(float2*)(p + base);
    float2 av = pv;
    #pragma unroll
    for (int s = 0; s < KSLAB; ++s) {
        float2 v = *(const float2*)(Vp + (size_t)s * NH + base);
        av.x += v.x; av.y += v.y;
    }
    red[t] = pv.x * av.x + pv.y * av.y;
    __syncthreads();
    for (int s = 128; s > 0; s >>= 1) { if (t < s) red[t] += red[t + s]; __syncthreads(); }
    if (t == 0) sAlpha = rho[n] / fmaxf(red[0], 1e-30f);
    __syncthreads();
    const float alpha = sAlpha;
    float2 xv = *(float2*)(xsol + base);
    xv.x += alpha * pv.x; xv.y += alpha * pv.y;
    *(float2*)(xsol + base) = xv;
    float2 rv = *(float2*)(r + base);
    rv.x -= alpha * av.x; rv.y -= alpha * av.y;
    *(float2*)(r + base) = rv;
    red[t] = rv.x * rv.x + rv.y * rv.y;
    __syncthreads();
    for (int s = 128; s > 0; s >>= 1) { if (t < s) red[t] += red[t + s]; __syncthreads(); }
    if (t == 0) { const float rn = red[0]; sBeta = rn / fmaxf(rho[n], 1e-30f); rho[n] = rn; }
    __syncthreads();
    const float beta = sBeta;
    pv.x = rv.x + beta * pv.x; pv.y = rv.y + beta * pv.y;
    *(float2*)(p + base) = pv;
    if (writeOut) { *(float2*)(outProx + base) = xv; }
}

// ---------------------------------------------------------------------------
extern "C" void kernel_launch(void* const* d_in, const int* in_sizes, int n_in,
                              void* d_out, int out_size, void* d_ws, size_t ws_size,
                              hipStream_t stream) {
    const float* x   = (const float*)d_in[0];
    const float* hx  = (const float*)d_in[1];
    const float* cx  = (const float*)d_in[2];
    const float* Wih = (const float*)d_in[3];
    const float* Whh = (const float*)d_in[4];
    const float* bih = (const float*)d_in[5];
    const float* bhh = (const float*)d_in[6];
    float* out = (float*)d_out;              // [h_new (131072) | prox_c (131072)]

    float* ws = (float*)d_ws;
    float* zp   = ws;                          // 2 * 524288
    float* Ci   = zp + 2 * 524288;
    float* Cf   = Ci + NH;
    float* Cg   = Cf + NH;
    float* xsol = Cg + NH;
    float* r    = xsol + NH;
    float* p    = r + NH;
    float* Qp   = p + NH;                      // 8 * NH
    float* Vp   = Qp + (size_t)KSLAB * NH;     // 8 * NH
    float* rho  = Vp + (size_t)KSLAB * NH;     // 256
    unsigned short* Wihb = (unsigned short*)(rho + 256);   // 2048*512
    unsigned short* Whhb = Wihb + 2048 * 512;              // 2048*512
    unsigned short* Wtb  = Whhb + 2048 * 512;              // 512*1536
    unsigned short* xb   = Wtb + 512 * 1536;               // 256*512
    unsigned short* hxb  = xb + NB * DD;                   // 256*512

    k_cvt<<<2304, 256, 0, stream>>>(Wih, Whh, x, hx, Wihb, Whhb, xb, hxb);
    k_tr<<<dim3(24, 8), 256, 0, stream>>>(Wih, Wtb);
    k_gemm_z<<<dim3(32, 4, 2), 256, 0, stream>>>(xb, hxb, Wihb, Whhb, zp);
    k_gates_init<<<NB, 256, 0, stream>>>(zp, cx, bih, bhh, out, Ci, Cf, Cg, xsol, r, p, rho);

    for (int it = 0; it < CG_ITERS; ++it) {
        k_gemm_q<<<dim3(8, 4, KSLAB), 256, 0, stream>>>(Wtb, Ci, Cf, Cg, p, Qp);
        k_gemm_ap<<<dim3(8, 4, KSLAB), 256, 0, stream>>>(Wihb, Qp, Ci, Cf, Cg, Vp);
        k_cg_update<<<NB, 256, 0, stream>>>(xsol, r, p, Vp, rho, out + NH,
                                            (it == CG_ITERS - 1) ? 1 : 0);
    }
}